// Round 13
// baseline (406.938 us; speedup 1.0000x reference)
//
#include <hip/hip_runtime.h>

// GNN NodeEncoder: 2 layers of
//   h = relu(x@Wr + br + mean_in(x[src])@W1 + mean_out(x[dst])@W2)
// Algebra: scatter_mean((x@W)[src],dst) == scatter_mean(x[src],dst)@W -> aggregate
// RAW features, apply weights after as an MFMA GEMM (split-bf16 hi/lo).
// CSR build BINNED (512-node buckets, r3: kills 16x write-allocate amplification).
// Gather history: r7/r9 A/B -> fetch-throughput-bound, concurrency exhausted;
// r10 fp16 table: FETCH 279->129MB, dur 100->74us but VALUBusy 29->48% (unpack+
// reduce overhead binding). This rev: LANE-PER-COLUMN gather -- one wave-wide
// ushort load per row (1 cvt + 1 add per lane), zero cross-lane reduce, scalar
// row indexing. Same bytes, ~1/3 the VALU.

typedef __bf16 bf16x8 __attribute__((ext_vector_type(8)));
typedef float  f32x4  __attribute__((ext_vector_type(4)));
typedef _Float16 half4 __attribute__((ext_vector_type(4)));

#define BSHIFT 9          // 512 nodes per bucket
#define NBMAX  256        // max buckets (N <= 131072, and id must fit 17 bits)
#define CAPLOG 13         // 8192 entries per bucket (mean 6378, sigma ~80 -> +22 sigma)
#define CAP    (1 << CAPLOG)

// ---------------- binned CSR build ----------------
__launch_bounds__(256)
__global__ void k_bin(const int* __restrict__ ei, int E,
                      int* __restrict__ gcnt /* [2*NBMAX] */,
                      unsigned* __restrict__ binbuf /* [2*NBMAX*CAP] */) {
    __shared__ int lcnt[2 * NBMAX];
    const int tid = threadIdx.x;
    lcnt[tid] = 0; lcnt[NBMAX + tid] = 0;
    __syncthreads();
    const int start = blockIdx.x * 8192;
    const int end = min(start + 8192, E);
    for (int e = start + tid; e < end; e += 256) {
        int s = ei[e], d = ei[E + e];
        atomicAdd(&lcnt[d >> BSHIFT], 1);           // in-dir: bucket by dst
        atomicAdd(&lcnt[NBMAX + (s >> BSHIFT)], 1); // out-dir: bucket by src
    }
    __syncthreads();
    {   // reserve contiguous runs in each bucket; cursor = global base
        int c0 = lcnt[tid], c1 = lcnt[NBMAX + tid];
        int b0 = c0 ? atomicAdd(&gcnt[tid], c0) : 0;
        int b1 = c1 ? atomicAdd(&gcnt[NBMAX + tid], c1) : 0;
        lcnt[tid] = b0; lcnt[NBMAX + tid] = b1;
    }
    __syncthreads();
    for (int e = start + tid; e < end; e += 256) {  // ei re-read is L2-hot
        int s = ei[e], d = ei[E + e];
        int bi = d >> BSHIFT;
        int p = atomicAdd(&lcnt[bi], 1);
        if (p < CAP)
            binbuf[(bi << CAPLOG) + p] = ((unsigned)(d & 511) << 17) | (unsigned)s;
        int bo = s >> BSHIFT;
        int p2 = atomicAdd(&lcnt[NBMAX + bo], 1);
        if (p2 < CAP)
            binbuf[((NBMAX + bo) << CAPLOG) + p2] = ((unsigned)(s & 511) << 17) | (unsigned)d;
    }
}

// Pass B: per (bucket,dir) block. In-LDS scan of gcnt -> bucket base; LDS degree
// histogram -> Blelloch exclusive scan -> write rp + scatter ci via LDS cursors.
__launch_bounds__(256)
__global__ void k_binfill2(const unsigned* __restrict__ binbuf, const int* __restrict__ gcnt,
                           int n,
                           int* __restrict__ rp_in, int* __restrict__ rp_out,
                           int* __restrict__ ci_in, int* __restrict__ ci_out) {
    __shared__ int h[512];     // histogram -> exclusive scan
    __shared__ int cur[512];   // scatter cursors
    __shared__ int gb[NBMAX];  // bucket-total scan for base offset
    __shared__ int s_tot;
    const int dir = blockIdx.y, bkt = blockIdx.x, tid = threadIdx.x;
    int* rp = dir ? rp_out : rp_in;
    int* ci = dir ? ci_out : ci_in;
    h[tid] = 0; h[256 + tid] = 0;
    gb[tid] = gcnt[dir * NBMAX + tid];
    __syncthreads();
    for (int off = 1; off < NBMAX; off <<= 1) {
        int t = (tid >= off) ? gb[tid - off] : 0;
        __syncthreads();
        gb[tid] += t;
        __syncthreads();
    }
    const int base_off = bkt ? gb[bkt - 1] : 0;
    const int cnt = min(gcnt[dir * NBMAX + bkt], CAP);
    const unsigned* buf = binbuf + (((size_t)dir * NBMAX + bkt) << CAPLOG);
    for (int i = tid; i < cnt; i += 256)
        atomicAdd(&h[buf[i] >> 17], 1);
    __syncthreads();
    for (int d = 1; d < 512; d <<= 1) {
        int idx = (tid + 1) * (d << 1) - 1;
        if (idx < 512) h[idx] += h[idx - d];
        __syncthreads();
    }
    if (tid == 0) { s_tot = h[511]; h[511] = 0; }
    __syncthreads();
    for (int d = 256; d >= 1; d >>= 1) {
        int idx = (tid + 1) * (d << 1) - 1;
        if (idx < 512) { int t = h[idx - d]; h[idx - d] = h[idx]; h[idx] += t; }
        __syncthreads();
    }
    const int nodebase = bkt << BSHIFT;
    for (int i = tid; i < 512; i += 256) {
        int nd = nodebase + i;
        int v = base_off + h[i];
        cur[i] = v;
        if (nd < n) rp[nd] = v;
    }
    if (tid == 0 && ((n - 1) >> BSHIFT) == bkt)
        rp[n] = base_off + s_tot;           // final row pointer
    __syncthreads();
    for (int i = tid; i < cnt; i += 256) {  // buf re-read is L2-hot (~25KB)
        unsigned ent = buf[i];
        int slot = atomicAdd(&cur[ent >> 17], 1);
        ci[slot] = (int)(ent & 0x1FFFFu);
    }
}

// ---------------- weight prep (both layers in one launch) ----------------
__global__ void k_prep2(const float* __restrict__ W1a, const float* __restrict__ W2a,
                        const float* __restrict__ Wra,
                        __bf16* __restrict__ WcTha, __bf16* __restrict__ WcTla,
                        __bf16* __restrict__ WrTha, __bf16* __restrict__ WrTla,
                        const float* __restrict__ W1b, const float* __restrict__ W2b,
                        const float* __restrict__ Wrb,
                        __bf16* __restrict__ WcThb, __bf16* __restrict__ WcTlb,
                        __bf16* __restrict__ WrThb, __bf16* __restrict__ WrTlb) {
    const float *W1, *W2, *Wr;
    __bf16 *Wch, *Wcl, *Wrh, *Wrl;
    if (blockIdx.y == 0) { W1 = W1a; W2 = W2a; Wr = Wra; Wch = WcTha; Wcl = WcTla; Wrh = WrTha; Wrl = WrTla; }
    else                 { W1 = W1b; W2 = W2b; Wr = Wrb; Wch = WcThb; Wcl = WcTlb; Wrh = WrThb; Wrl = WrTlb; }
    int i = blockIdx.x * 256 + threadIdx.x;  // 12288 total
    if (i < 8192) {
        int nn = i >> 7, k = i & 127;
        float w = (k < 64) ? W1[k * 64 + nn] : W2[(k - 64) * 64 + nn];
        __bf16 h = (__bf16)w;
        Wch[i] = h;
        Wcl[i] = (__bf16)(w - (float)h);
    } else if (i < 12288) {
        int j = i - 8192;
        int nn = j >> 6, k = j & 63;
        float w = Wr[k * 64 + nn];
        __bf16 h = (__bf16)w;
        Wrh[j] = h;
        Wrl[j] = (__bf16)(w - (float)h);
    }
}

// ---------------- fp32 -> fp16 feature table (layer-1 input) ----------------
__global__ void k_tohalf(const float* __restrict__ X, _Float16* __restrict__ F, int n64) {
    int i = (blockIdx.x * 256 + threadIdx.x) * 4;
    if (i >= n64) return;
    float4 v = *(const float4*)(X + i);
    half4 h = { (_Float16)v.x, (_Float16)v.y, (_Float16)v.z, (_Float16)v.w };
    *(half4*)(F + i) = h;
}

// ---------------- gather: lane-per-column, scalar row indexing ----------------
// lane c owns feature column c for ALL rows of its node: one wave-wide ushort
// load per row (64x2B = one 128B coalesced transaction), 1 cvt + 1 add per lane,
// NO cross-lane reduce. Row bounds/indices hoisted to SGPRs (readfirstlane) so
// index fetch + row-address math ride the scalar pipes. 8-deep unroll = 8 rows
// in flight per wave.
__launch_bounds__(256, 8)
__global__ void k_gather(const _Float16* __restrict__ F,
                         const int* __restrict__ rp_in, const int* __restrict__ ci_in,
                         const int* __restrict__ rp_out, const int* __restrict__ ci_out,
                         __bf16* __restrict__ Ah, __bf16* __restrict__ Al, int n) {
    const int lane = threadIdx.x & 63;
    const int wid  = threadIdx.x >> 6;
    const int v = blockIdx.x * 4 + wid;
    if (v >= n) return;
    const _Float16* __restrict__ col = F + lane;   // stride 64 elems per row

    #pragma unroll
    for (int dir = 0; dir < 2; ++dir) {
        const int* __restrict__ rp = dir ? rp_out : rp_in;
        const int* __restrict__ ci = dir ? ci_out : ci_in;
        const int s = __builtin_amdgcn_readfirstlane(rp[v]);
        const int e = __builtin_amdgcn_readfirstlane(rp[v + 1]);
        float acc = 0.f;
        int t = s;
        for (; t + 8 <= e; t += 8) {           // 8 rows in flight
            int u0 = __builtin_amdgcn_readfirstlane(ci[t]);
            int u1 = __builtin_amdgcn_readfirstlane(ci[t + 1]);
            int u2 = __builtin_amdgcn_readfirstlane(ci[t + 2]);
            int u3 = __builtin_amdgcn_readfirstlane(ci[t + 3]);
            int u4 = __builtin_amdgcn_readfirstlane(ci[t + 4]);
            int u5 = __builtin_amdgcn_readfirstlane(ci[t + 5]);
            int u6 = __builtin_amdgcn_readfirstlane(ci[t + 6]);
            int u7 = __builtin_amdgcn_readfirstlane(ci[t + 7]);
            _Float16 h0 = col[(size_t)u0 * 64];
            _Float16 h1 = col[(size_t)u1 * 64];
            _Float16 h2 = col[(size_t)u2 * 64];
            _Float16 h3 = col[(size_t)u3 * 64];
            _Float16 h4 = col[(size_t)u4 * 64];
            _Float16 h5 = col[(size_t)u5 * 64];
            _Float16 h6 = col[(size_t)u6 * 64];
            _Float16 h7 = col[(size_t)u7 * 64];
            acc += (float)h0 + (float)h1 + (float)h2 + (float)h3
                 + (float)h4 + (float)h5 + (float)h6 + (float)h7;
        }
        for (; t < e; ++t) {
            int u = __builtin_amdgcn_readfirstlane(ci[t]);
            acc += (float)col[(size_t)u * 64];
        }
        acc *= 1.0f / (float)max(e - s, 1);

        __bf16 hh = (__bf16)acc;
        __bf16 hl = (__bf16)(acc - (float)hh);
        size_t off = (size_t)v * 128 + dir * 64 + lane;   // 64x2B contiguous
        Ah[off] = hh;
        Al[off] = hl;
    }
}

// ---------------- MFMA GEMM: out = relu(A@Wcat + Hin@Wr + br) ----------------
// mfma_f32_16x16x32_bf16; identical k-packing for A and B cancels internal
// k-order. C/D: col = lane&15, row = (lane>>4)*4 + reg  [verified m89]
// Optionally also stores the output as fp16 (feature table for next layer's gather).
__global__ void k_gemm(const __bf16* __restrict__ Ah, const __bf16* __restrict__ Al,
                       const float* __restrict__ Hin,
                       const __bf16* __restrict__ WcT_h, const __bf16* __restrict__ WcT_l,
                       const __bf16* __restrict__ WrT_h, const __bf16* __restrict__ WrT_l,
                       const float* __restrict__ br, float* __restrict__ Hout,
                       _Float16* __restrict__ Fout, int n) {
    const int lane = threadIdx.x & 63;
    const int wid  = threadIdx.x >> 6;
    const int q = lane & 15, sub = lane >> 4;
    const int rowbase = blockIdx.x * 64 + wid * 16;
    const int arow = min(rowbase + q, n - 1);

    f32x4 acc[4];
    #pragma unroll
    for (int nf = 0; nf < 4; ++nf) acc[nf] = (f32x4){0.f, 0.f, 0.f, 0.f};

    // A @ Wcat  (K = 128)
    #pragma unroll
    for (int ks = 0; ks < 4; ++ks) {
        const size_t ao = (size_t)arow * 128 + ks * 32 + sub * 8;
        bf16x8 a_h = *(const bf16x8*)(Ah + ao);
        bf16x8 a_l = *(const bf16x8*)(Al + ao);
        #pragma unroll
        for (int nf = 0; nf < 4; ++nf) {
            const size_t bo = (size_t)(nf * 16 + q) * 128 + ks * 32 + sub * 8;
            bf16x8 b_h = *(const bf16x8*)(WcT_h + bo);
            bf16x8 b_l = *(const bf16x8*)(WcT_l + bo);
            acc[nf] = __builtin_amdgcn_mfma_f32_16x16x32_bf16(a_h, b_h, acc[nf], 0, 0, 0);
            acc[nf] = __builtin_amdgcn_mfma_f32_16x16x32_bf16(a_h, b_l, acc[nf], 0, 0, 0);
            acc[nf] = __builtin_amdgcn_mfma_f32_16x16x32_bf16(a_l, b_h, acc[nf], 0, 0, 0);
        }
    }
    // Hin @ Wr  (K = 64), fp32 -> hi/lo split in-register
    #pragma unroll
    for (int ks = 0; ks < 2; ++ks) {
        const float* hp = Hin + (size_t)arow * 64 + ks * 32 + sub * 8;
        float4 h0 = *(const float4*)hp;
        float4 h1 = *(const float4*)(hp + 4);
        float hf[8] = {h0.x, h0.y, h0.z, h0.w, h1.x, h1.y, h1.z, h1.w};
        bf16x8 a_h, a_l;
        #pragma unroll
        for (int c = 0; c < 8; ++c) {
            __bf16 h = (__bf16)hf[c];
            a_h[c] = h;
            a_l[c] = (__bf16)(hf[c] - (float)h);
        }
        #pragma unroll
        for (int nf = 0; nf < 4; ++nf) {
            const size_t bo = (size_t)(nf * 16 + q) * 64 + ks * 32 + sub * 8;
            bf16x8 b_h = *(const bf16x8*)(WrT_h + bo);
            bf16x8 b_l = *(const bf16x8*)(WrT_l + bo);
            acc[nf] = __builtin_amdgcn_mfma_f32_16x16x32_bf16(a_h, b_h, acc[nf], 0, 0, 0);
            acc[nf] = __builtin_amdgcn_mfma_f32_16x16x32_bf16(a_h, b_l, acc[nf], 0, 0, 0);
            acc[nf] = __builtin_amdgcn_mfma_f32_16x16x32_bf16(a_l, b_h, acc[nf], 0, 0, 0);
        }
    }
    #pragma unroll
    for (int nf = 0; nf < 4; ++nf) {
        int col = nf * 16 + q;
        float b = br[col];
        #pragma unroll
        for (int reg = 0; reg < 4; ++reg) {
            int row = rowbase + sub * 4 + reg;
            if (row < n) {
                float val = fmaxf(acc[nf][reg] + b, 0.f);
                Hout[(size_t)row * 64 + col] = val;
                if (Fout) Fout[(size_t)row * 64 + col] = (_Float16)val;
            }
        }
    }
}

extern "C" void kernel_launch(void* const* d_in, const int* in_sizes, int n_in,
                              void* d_out, int out_size, void* d_ws, size_t ws_size,
                              hipStream_t stream) {
    const float* x    = (const float*)d_in[0];
    const int*   ei   = (const int*)d_in[1];
    const float* W1_0 = (const float*)d_in[2];
    const float* W2_0 = (const float*)d_in[3];
    const float* Wr_0 = (const float*)d_in[4];
    const float* br_0 = (const float*)d_in[5];
    const float* W1_1 = (const float*)d_in[6];
    const float* W2_1 = (const float*)d_in[7];
    const float* Wr_1 = (const float*)d_in[8];
    const float* br_1 = (const float*)d_in[9];
    float* out = (float*)d_out;

    const int N = in_sizes[0] / 64;
    const int E = in_sizes[1] / 2;
    const int NB = (N + 511) >> BSHIFT;       // 196 buckets (<= NBMAX)

    // bump allocator over d_ws (re-poisoned every call -> rebuild everything)
    char* p = (char*)d_ws;
    auto alloc = [&](size_t bytes) { char* r = p; p += (bytes + 255) & ~255ULL; return r; };

    int* rp_in   = (int*)alloc(((size_t)N + 1) * 4);
    int* rp_out  = (int*)alloc(((size_t)N + 1) * 4);
    int* gcnt    = (int*)alloc(2 * NBMAX * 4);
    int* ci_in   = (int*)alloc((size_t)E * 4);
    int* ci_out  = (int*)alloc((size_t)E * 4);
    __bf16* Ah   = (__bf16*)alloc((size_t)N * 128 * 2);
    __bf16* Al   = (__bf16*)alloc((size_t)N * 128 * 2);
    float* H     = (float*)alloc((size_t)N * 64 * 4);
    _Float16* F  = (_Float16*)alloc((size_t)N * 64 * 2);   // fp16 gather table (x, then H)
    __bf16* WcT_h0 = (__bf16*)alloc(8192 * 2);
    __bf16* WcT_l0 = (__bf16*)alloc(8192 * 2);
    __bf16* WrT_h0 = (__bf16*)alloc(4096 * 2);
    __bf16* WrT_l0 = (__bf16*)alloc(4096 * 2);
    __bf16* WcT_h1 = (__bf16*)alloc(8192 * 2);
    __bf16* WcT_l1 = (__bf16*)alloc(8192 * 2);
    __bf16* WrT_h1 = (__bf16*)alloc(4096 * 2);
    __bf16* WrT_l1 = (__bf16*)alloc(4096 * 2);

    // binbuf (2*NBMAX*CAP*4B = 16.8MB) aliases Ah/Al: dead before first k_gather.
    unsigned* binbuf = (unsigned*)Ah;

    hipMemsetAsync(gcnt, 0, 2 * NBMAX * 4, stream);

    int bb = (E + 8191) / 8192;
    k_bin<<<bb, 256, 0, stream>>>(ei, E, gcnt, binbuf);
    k_binfill2<<<dim3(NB, 2), 256, 0, stream>>>(binbuf, gcnt, N,
                                                rp_in, rp_out, ci_in, ci_out);
    k_prep2<<<dim3(48, 2), 256, 0, stream>>>(W1_0, W2_0, Wr_0, WcT_h0, WcT_l0, WrT_h0, WrT_l0,
                                             W1_1, W2_1, Wr_1, WcT_h1, WcT_l1, WrT_h1, WrT_l1);
    k_tohalf<<<(N * 64 / 4 + 255) / 256, 256, 0, stream>>>(x, F, N * 64);

    int gb = (N + 3) / 4;           // 4 nodes per 256-thread block
    int mb = (N + 63) / 64;         // 64 rows per GEMM block

    k_gather<<<gb, 256, 0, stream>>>(F, rp_in, ci_in, rp_out, ci_out, Ah, Al, N);
    k_gemm<<<mb, 256, 0, stream>>>(Ah, Al, x, WcT_h0, WcT_l0, WrT_h0, WrT_l0, br_0, H, F, N);

    k_gather<<<gb, 256, 0, stream>>>(F, rp_in, ci_in, rp_out, ci_out, Ah, Al, N);
    k_gemm<<<mb, 256, 0, stream>>>(Ah, Al, H, WcT_h1, WcT_l1, WrT_h1, WrT_l1, br_1, out,
                                   (_Float16*)nullptr, N);
}